// Round 1
// baseline (725.342 us; speedup 1.0000x reference)
//
#include <hip/hip_runtime.h>

// 2-layer tanh RNN, B=2048 T=512 I=5 H=64 O=1.
// Design: one wave64 per batch element (2048 waves = 2 waves/SIMD chip-wide).
// Lane i owns h1[i], h2[i] and the i-th rows of W_hh0/W_ih1/W_hh1 in VGPRs.
// Cross-lane h[j] broadcast via v_readlane -> SGPR operand of v_fmac:
// 1 readlane + 1 fma per MAC, all on the VALU pipe (no LDS, no barriers).

constexpr int Bn = 2048;
constexpr int Tn = 512;
constexpr int In = 5;
constexpr int Hn = 64;

__device__ __forceinline__ float lane_f(float v, int l) {
    return __int_as_float(__builtin_amdgcn_readlane(__float_as_int(v), l));
}

// tanh(v) = (e^{2v}-1)/(e^{2v}+1); clamp so e^{2v} can't overflow to inf.
// v_exp_f32 is ~1ulp; v_rcp ~1e-7 rel -- far below the 8e-3 absmax threshold.
__device__ __forceinline__ float fast_tanh(float v) {
    v = fminf(fmaxf(v, -15.f), 15.f);
    float e = __expf(2.f * v);
    return (e - 1.f) * __builtin_amdgcn_rcpf(e + 1.f);
}

__global__ __launch_bounds__(256, 2) void rnn2_fused(
    const float* __restrict__ x,
    const float* __restrict__ W_ih0, const float* __restrict__ W_hh0,
    const float* __restrict__ b_ih0, const float* __restrict__ b_hh0,
    const float* __restrict__ W_ih1, const float* __restrict__ W_hh1,
    const float* __restrict__ b_ih1, const float* __restrict__ b_hh1,
    const float* __restrict__ fc_W, const float* __restrict__ fc_b,
    float* __restrict__ out)
{
    const int lane = threadIdx.x & 63;
    int b = (blockIdx.x << 2) + (threadIdx.x >> 6);
    b = __builtin_amdgcn_readfirstlane(b);   // force wave-uniform -> s_loads for x

    // ---- stage weights into per-lane registers (rows of each matrix) ----
    float wih0[In];
    #pragma unroll
    for (int j = 0; j < In; ++j) wih0[j] = W_ih0[lane * In + j];

    float whh0[Hn], wih1[Hn], whh1[Hn];
    {
        const float4* p0 = reinterpret_cast<const float4*>(W_hh0) + lane * (Hn / 4);
        const float4* p1 = reinterpret_cast<const float4*>(W_ih1) + lane * (Hn / 4);
        const float4* p2 = reinterpret_cast<const float4*>(W_hh1) + lane * (Hn / 4);
        #pragma unroll
        for (int k = 0; k < Hn / 4; ++k) {
            float4 v0 = p0[k];
            whh0[4*k+0] = v0.x; whh0[4*k+1] = v0.y; whh0[4*k+2] = v0.z; whh0[4*k+3] = v0.w;
            float4 v1 = p1[k];
            wih1[4*k+0] = v1.x; wih1[4*k+1] = v1.y; wih1[4*k+2] = v1.z; wih1[4*k+3] = v1.w;
            float4 v2 = p2[k];
            whh1[4*k+0] = v2.x; whh1[4*k+1] = v2.y; whh1[4*k+2] = v2.z; whh1[4*k+3] = v2.w;
        }
    }

    const float bias0 = b_ih0[lane] + b_hh0[lane];
    const float bias1 = b_ih1[lane] + b_hh1[lane];

    float h1 = 0.f, h2 = 0.f;

    const float* xp = x + (size_t)b * (Tn * In);
    float xv[In];
    #pragma unroll
    for (int j = 0; j < In; ++j) xv[j] = xp[j];

    #pragma unroll 1
    for (int t = 0; t < Tn; ++t) {
        // prefetch next step's x early so the (uniform, scalar) load latency
        // hides under this step's ~400 VALU ops; clamped index avoids OOB.
        const int tn = (t + 1 < Tn) ? (t + 1) : (Tn - 1);
        const float* xq = xp + tn * In;
        float xn[In];
        #pragma unroll
        for (int j = 0; j < In; ++j) xn[j] = xq[j];

        // ---- layer 1: h1 = tanh(Wih0 x_t + Whh0 h1 + b) ----
        float a0 = bias0, a1 = 0.f, a2 = 0.f, a3 = 0.f;  // 4 chains for FMA-latency ILP
        #pragma unroll
        for (int j = 0; j < In; ++j) a0 += wih0[j] * xv[j];
        #pragma unroll
        for (int j = 0; j < Hn; j += 4) {
            a0 += whh0[j+0] * lane_f(h1, j+0);
            a1 += whh0[j+1] * lane_f(h1, j+1);
            a2 += whh0[j+2] * lane_f(h1, j+2);
            a3 += whh0[j+3] * lane_f(h1, j+3);
        }
        h1 = fast_tanh((a0 + a1) + (a2 + a3));

        // ---- layer 2: h2 = tanh(Wih1 h1 + Whh1 h2 + b) ----
        float c0 = bias1, c1 = 0.f, c2 = 0.f, c3 = 0.f;
        #pragma unroll
        for (int j = 0; j < Hn; j += 2) {
            c0 += wih1[j+0] * lane_f(h1, j+0);
            c1 += wih1[j+1] * lane_f(h1, j+1);
            c2 += whh1[j+0] * lane_f(h2, j+0);
            c3 += whh1[j+1] * lane_f(h2, j+1);
        }
        h2 = fast_tanh((c0 + c1) + (c2 + c3));

        #pragma unroll
        for (int j = 0; j < In; ++j) xv[j] = xn[j];
    }

    // ---- fc: out[b] = fc_W . h2 + fc_b ----
    float contrib = fc_W[lane] * h2;
    #pragma unroll
    for (int off = 32; off; off >>= 1)
        contrib += __shfl_xor(contrib, off, 64);
    if (lane == 0) out[b] = contrib + fc_b[0];
}

extern "C" void kernel_launch(void* const* d_in, const int* in_sizes, int n_in,
                              void* d_out, int out_size, void* d_ws, size_t ws_size,
                              hipStream_t stream) {
    const float* x     = (const float*)d_in[0];
    const float* W_ih0 = (const float*)d_in[1];
    const float* W_hh0 = (const float*)d_in[2];
    const float* b_ih0 = (const float*)d_in[3];
    const float* b_hh0 = (const float*)d_in[4];
    const float* W_ih1 = (const float*)d_in[5];
    const float* W_hh1 = (const float*)d_in[6];
    const float* b_ih1 = (const float*)d_in[7];
    const float* b_hh1 = (const float*)d_in[8];
    const float* fc_W  = (const float*)d_in[9];
    const float* fc_b  = (const float*)d_in[10];
    float* out = (float*)d_out;

    dim3 grid(Bn / 4);   // 512 blocks x 4 waves = 2048 waves, one per batch row
    dim3 block(256);
    hipLaunchKernelGGL(rnn2_fused, grid, block, 0, stream,
                       x, W_ih0, W_hh0, b_ih0, b_hh0,
                       W_ih1, W_hh1, b_ih1, b_hh1, fc_W, fc_b, out);
}

// Round 3
// 690.205 us; speedup vs baseline: 1.0509x; 1.0509x over previous
//
#include <hip/hip_runtime.h>

// 2-layer tanh RNN, B=2048 T=512 I=5 H=64 O=1.
// One wave64 per batch element (2048 waves = 2 waves/SIMD chip-wide).
// Lane i owns h1[i], h2[i] and row i of W_hh0/W_ih1/W_hh1 in VGPRs.
// Cross-lane h[j] broadcast via v_readlane -> SGPR operand of v_fmac:
// 2 VALU ops per 64-MAC group (readlane + fmac), no LDS, no barriers.
//
// R1 fix: VGPR_Count=112 showed the compiler sank the 192 weight loads into
// the t-loop (rematerialization) -> ~80 extra instr/step + vmcnt stalls.
// Pin every weight through an empty asm so it is NOT rematerializable and
// must stay register-resident (budget ~230 < 256 cap at launch_bounds(256,2)).
// R2 fix: __builtin_amdgcn_expf does not exist -> __builtin_amdgcn_exp2f.

constexpr int Bn = 2048;
constexpr int Tn = 512;
constexpr int In = 5;
constexpr int Hn = 64;

__device__ __forceinline__ float lane_f(float v, int l) {
    return __int_as_float(__builtin_amdgcn_readlane(__float_as_int(v), l));
}

// tanh(v) = (e-1)/(e+1), e = 2^(2*log2(e)*v); clamp via v_med3 so e can't
// overflow. v_exp_f32 ~1ulp, v_rcp ~1e-7 rel -- way below 8e-3 threshold.
__device__ __forceinline__ float fast_tanh(float v) {
    v = __builtin_amdgcn_fmed3f(v, -15.f, 15.f);             // 1-op clamp
    float e = __builtin_amdgcn_exp2f(v * 2.885390082f);      // 2^(2*log2e*v)
    return (e - 1.f) * __builtin_amdgcn_rcpf(e + 1.f);
}

__device__ __forceinline__ void pin(float& v) {
    asm volatile("" : "+v"(v));   // opaque def: not rematerializable
}

__global__ __launch_bounds__(256, 2) void rnn2_fused(
    const float* __restrict__ x,
    const float* __restrict__ W_ih0, const float* __restrict__ W_hh0,
    const float* __restrict__ b_ih0, const float* __restrict__ b_hh0,
    const float* __restrict__ W_ih1, const float* __restrict__ W_hh1,
    const float* __restrict__ b_ih1, const float* __restrict__ b_hh1,
    const float* __restrict__ fc_W, const float* __restrict__ fc_b,
    float* __restrict__ out)
{
    const int lane = threadIdx.x & 63;
    int b = (blockIdx.x << 2) + (threadIdx.x >> 6);
    b = __builtin_amdgcn_readfirstlane(b);   // wave-uniform -> scalar x loads

    // ---- stage weights into per-lane registers (rows of each matrix) ----
    float wih0[In];
    #pragma unroll
    for (int j = 0; j < In; ++j) wih0[j] = W_ih0[lane * In + j];

    float whh0[Hn], wih1[Hn], whh1[Hn];
    {
        const float4* p0 = reinterpret_cast<const float4*>(W_hh0) + lane * (Hn / 4);
        const float4* p1 = reinterpret_cast<const float4*>(W_ih1) + lane * (Hn / 4);
        const float4* p2 = reinterpret_cast<const float4*>(W_hh1) + lane * (Hn / 4);
        #pragma unroll
        for (int k = 0; k < Hn / 4; ++k) {
            float4 v0 = p0[k];
            whh0[4*k+0] = v0.x; whh0[4*k+1] = v0.y; whh0[4*k+2] = v0.z; whh0[4*k+3] = v0.w;
            float4 v1 = p1[k];
            wih1[4*k+0] = v1.x; wih1[4*k+1] = v1.y; wih1[4*k+2] = v1.z; wih1[4*k+3] = v1.w;
            float4 v2 = p2[k];
            whh1[4*k+0] = v2.x; whh1[4*k+1] = v2.y; whh1[4*k+2] = v2.z; whh1[4*k+3] = v2.w;
        }
    }

    // Force register residency: asm results cannot be rematerialized from
    // the original loads, so the allocator must keep them live in VGPRs.
    #pragma unroll
    for (int j = 0; j < In; ++j) pin(wih0[j]);
    #pragma unroll
    for (int j = 0; j < Hn; ++j) { pin(whh0[j]); pin(wih1[j]); pin(whh1[j]); }

    const float bias0 = b_ih0[lane] + b_hh0[lane];
    const float bias1 = b_ih1[lane] + b_hh1[lane];

    float h1 = 0.f, h2 = 0.f;

    const float* xp = x + (size_t)b * (Tn * In);
    float xv[In];
    #pragma unroll
    for (int j = 0; j < In; ++j) xv[j] = xp[j];

    #pragma unroll 1
    for (int t = 0; t < Tn; ++t) {
        // prefetch next step's x so the uniform load latency hides under
        // this step's ~420 VALU ops; clamped index avoids OOB.
        const int tn = (t + 1 < Tn) ? (t + 1) : (Tn - 1);
        const float* xq = xp + tn * In;
        float xn[In];
        #pragma unroll
        for (int j = 0; j < In; ++j) xn[j] = xq[j];

        // ---- layer 1: h1 = tanh(Wih0 x_t + Whh0 h1 + b) ----
        float a0 = bias0, a1 = 0.f, a2 = 0.f, a3 = 0.f;  // 4 chains for ILP
        #pragma unroll
        for (int j = 0; j < In; ++j) a0 += wih0[j] * xv[j];
        #pragma unroll
        for (int j = 0; j < Hn; j += 4) {
            a0 += whh0[j+0] * lane_f(h1, j+0);
            a1 += whh0[j+1] * lane_f(h1, j+1);
            a2 += whh0[j+2] * lane_f(h1, j+2);
            a3 += whh0[j+3] * lane_f(h1, j+3);
        }
        h1 = fast_tanh((a0 + a1) + (a2 + a3));

        // ---- layer 2: h2 = tanh(Wih1 h1 + Whh1 h2 + b) ----
        float c0 = bias1, c1 = 0.f, c2 = 0.f, c3 = 0.f;
        #pragma unroll
        for (int j = 0; j < Hn; j += 2) {
            c0 += wih1[j+0] * lane_f(h1, j+0);
            c1 += wih1[j+1] * lane_f(h1, j+1);
            c2 += whh1[j+0] * lane_f(h2, j+0);
            c3 += whh1[j+1] * lane_f(h2, j+1);
        }
        h2 = fast_tanh((c0 + c1) + (c2 + c3));

        #pragma unroll
        for (int j = 0; j < In; ++j) xv[j] = xn[j];
    }

    // ---- fc: out[b] = fc_W . h2 + fc_b ----
    float contrib = fc_W[lane] * h2;
    #pragma unroll
    for (int off = 32; off; off >>= 1)
        contrib += __shfl_xor(contrib, off, 64);
    if (lane == 0) out[b] = contrib + fc_b[0];
}

extern "C" void kernel_launch(void* const* d_in, const int* in_sizes, int n_in,
                              void* d_out, int out_size, void* d_ws, size_t ws_size,
                              hipStream_t stream) {
    const float* x     = (const float*)d_in[0];
    const float* W_ih0 = (const float*)d_in[1];
    const float* W_hh0 = (const float*)d_in[2];
    const float* b_ih0 = (const float*)d_in[3];
    const float* b_hh0 = (const float*)d_in[4];
    const float* W_ih1 = (const float*)d_in[5];
    const float* W_hh1 = (const float*)d_in[6];
    const float* b_ih1 = (const float*)d_in[7];
    const float* b_hh1 = (const float*)d_in[8];
    const float* fc_W  = (const float*)d_in[9];
    const float* fc_b  = (const float*)d_in[10];
    float* out = (float*)d_out;

    dim3 grid(Bn / 4);   // 512 blocks x 4 waves = 2048 waves, one per batch
    dim3 block(256);
    hipLaunchKernelGGL(rnn2_fused, grid, block, 0, stream,
                       x, W_ih0, W_hh0, b_ih0, b_hh0,
                       W_ih1, W_hh1, b_ih1, b_hh1, fc_W, fc_b, out);
}

// Round 4
// 687.889 us; speedup vs baseline: 1.0544x; 1.0034x over previous
//
#include <hip/hip_runtime.h>

// 2-layer tanh RNN, B=2048 T=512 I=5 H=64 O=1.
// One wave64 per batch element. Lane i owns h1[i], h2[i] and row i of
// W_hh0/W_ih1/W_hh1 in VGPRs. Cross-lane h[j] broadcast via v_readlane ->
// SGPR operand of v_fmac: 2 VALU ops per 64-MAC group, no LDS, no barriers.
//
// R3 post-mortem: at __launch_bounds__(256,2) the unified reg budget is
// 256/wave; compiler allocated 112 arch VGPR + 144 AGPR (=256 exactly) and
// pays v_accvgpr_read per weight per step (~192 extra instr/step, matches
// the measured 670 vs modeled 405 instr/step). Fix: launch_bounds(256,1)
// -> 512 unified budget -> all ~237 live values fit in arch VGPRs (<=256
// encoding cap). Trade: 1 wave/SIMD (no co-wave hiding) -- acceptable, the
// loop is dependency-lean and x is prefetched a full step ahead.

constexpr int Bn = 2048;
constexpr int Tn = 512;
constexpr int In = 5;
constexpr int Hn = 64;

__device__ __forceinline__ float lane_f(float v, int l) {
    return __int_as_float(__builtin_amdgcn_readlane(__float_as_int(v), l));
}

// tanh(v) = (e-1)/(e+1), e = 2^(2*log2(e)*v); clamp via v_med3 so e can't
// overflow. v_exp_f32 ~1ulp, v_rcp ~1e-7 rel -- way below 8e-3 threshold.
__device__ __forceinline__ float fast_tanh(float v) {
    v = __builtin_amdgcn_fmed3f(v, -15.f, 15.f);             // 1-op clamp
    float e = __builtin_amdgcn_exp2f(v * 2.885390082f);      // 2^(2*log2e*v)
    return (e - 1.f) * __builtin_amdgcn_rcpf(e + 1.f);
}

__device__ __forceinline__ void pin(float& v) {
    asm volatile("" : "+v"(v));   // opaque def: not rematerializable
}

__global__ __launch_bounds__(256, 1) void rnn2_fused(
    const float* __restrict__ x,
    const float* __restrict__ W_ih0, const float* __restrict__ W_hh0,
    const float* __restrict__ b_ih0, const float* __restrict__ b_hh0,
    const float* __restrict__ W_ih1, const float* __restrict__ W_hh1,
    const float* __restrict__ b_ih1, const float* __restrict__ b_hh1,
    const float* __restrict__ fc_W, const float* __restrict__ fc_b,
    float* __restrict__ out)
{
    const int lane = threadIdx.x & 63;
    int b = (blockIdx.x << 2) + (threadIdx.x >> 6);
    b = __builtin_amdgcn_readfirstlane(b);   // wave-uniform -> scalar x loads

    // ---- stage weights into per-lane registers (rows of each matrix) ----
    float wih0[In];
    #pragma unroll
    for (int j = 0; j < In; ++j) wih0[j] = W_ih0[lane * In + j];

    float whh0[Hn], wih1[Hn], whh1[Hn];
    {
        const float4* p0 = reinterpret_cast<const float4*>(W_hh0) + lane * (Hn / 4);
        const float4* p1 = reinterpret_cast<const float4*>(W_ih1) + lane * (Hn / 4);
        const float4* p2 = reinterpret_cast<const float4*>(W_hh1) + lane * (Hn / 4);
        #pragma unroll
        for (int k = 0; k < Hn / 4; ++k) {
            float4 v0 = p0[k];
            whh0[4*k+0] = v0.x; whh0[4*k+1] = v0.y; whh0[4*k+2] = v0.z; whh0[4*k+3] = v0.w;
            float4 v1 = p1[k];
            wih1[4*k+0] = v1.x; wih1[4*k+1] = v1.y; wih1[4*k+2] = v1.z; wih1[4*k+3] = v1.w;
            float4 v2 = p2[k];
            whh1[4*k+0] = v2.x; whh1[4*k+1] = v2.y; whh1[4*k+2] = v2.z; whh1[4*k+3] = v2.w;
        }
    }

    // Keep weights register-resident (not re-loadable/rematerializable).
    #pragma unroll
    for (int j = 0; j < In; ++j) pin(wih0[j]);
    #pragma unroll
    for (int j = 0; j < Hn; ++j) { pin(whh0[j]); pin(wih1[j]); pin(whh1[j]); }

    const float bias0 = b_ih0[lane] + b_hh0[lane];
    const float bias1 = b_ih1[lane] + b_hh1[lane];

    float h1 = 0.f, h2 = 0.f;

    const float* xp = x + (size_t)b * (Tn * In);
    float xv[In];
    #pragma unroll
    for (int j = 0; j < In; ++j) xv[j] = xp[j];

    #pragma unroll 1
    for (int t = 0; t < Tn; ++t) {
        // prefetch next step's x so the uniform load latency (~900 cyc HBM
        // worst-case) hides under this step's ~900 cyc of VALU work.
        const int tn = (t + 1 < Tn) ? (t + 1) : (Tn - 1);
        const float* xq = xp + tn * In;
        float xn[In];
        #pragma unroll
        for (int j = 0; j < In; ++j) xn[j] = xq[j];

        // ---- layer 1: h1 = tanh(Wih0 x_t + Whh0 h1 + b) ----
        float a0 = bias0, a1 = 0.f, a2 = 0.f, a3 = 0.f;  // 4 chains for ILP
        #pragma unroll
        for (int j = 0; j < In; ++j) a0 += wih0[j] * xv[j];
        #pragma unroll
        for (int j = 0; j < Hn; j += 4) {
            a0 += whh0[j+0] * lane_f(h1, j+0);
            a1 += whh0[j+1] * lane_f(h1, j+1);
            a2 += whh0[j+2] * lane_f(h1, j+2);
            a3 += whh0[j+3] * lane_f(h1, j+3);
        }
        h1 = fast_tanh((a0 + a1) + (a2 + a3));

        // ---- layer 2: h2 = tanh(Wih1 h1 + Whh1 h2 + b) ----
        float c0 = bias1, c1 = 0.f, c2 = 0.f, c3 = 0.f;
        #pragma unroll
        for (int j = 0; j < Hn; j += 2) {
            c0 += wih1[j+0] * lane_f(h1, j+0);
            c1 += wih1[j+1] * lane_f(h1, j+1);
            c2 += whh1[j+0] * lane_f(h2, j+0);
            c3 += whh1[j+1] * lane_f(h2, j+1);
        }
        h2 = fast_tanh((c0 + c1) + (c2 + c3));

        #pragma unroll
        for (int j = 0; j < In; ++j) xv[j] = xn[j];
    }

    // ---- fc: out[b] = fc_W . h2 + fc_b ----
    float contrib = fc_W[lane] * h2;
    #pragma unroll
    for (int off = 32; off; off >>= 1)
        contrib += __shfl_xor(contrib, off, 64);
    if (lane == 0) out[b] = contrib + fc_b[0];
}

extern "C" void kernel_launch(void* const* d_in, const int* in_sizes, int n_in,
                              void* d_out, int out_size, void* d_ws, size_t ws_size,
                              hipStream_t stream) {
    const float* x     = (const float*)d_in[0];
    const float* W_ih0 = (const float*)d_in[1];
    const float* W_hh0 = (const float*)d_in[2];
    const float* b_ih0 = (const float*)d_in[3];
    const float* b_hh0 = (const float*)d_in[4];
    const float* W_ih1 = (const float*)d_in[5];
    const float* W_hh1 = (const float*)d_in[6];
    const float* b_ih1 = (const float*)d_in[7];
    const float* b_hh1 = (const float*)d_in[8];
    const float* fc_W  = (const float*)d_in[9];
    const float* fc_b  = (const float*)d_in[10];
    float* out = (float*)d_out;

    dim3 grid(Bn / 4);   // 512 blocks x 4 waves = 2048 waves, one per batch
    dim3 block(256);
    hipLaunchKernelGGL(rnn2_fused, grid, block, 0, stream,
                       x, W_ih0, W_hh0, b_ih0, b_hh0,
                       W_ih1, W_hh1, b_ih1, b_hh1, fc_W, fc_b, out);
}